// Round 2
// baseline (1138.861 us; speedup 1.0000x reference)
//
#include <hip/hip_runtime.h>

// ---------------------------------------------------------------------------
// Fused 4-expert MoE actor:  gate(softmax) -> L1(relu) -> L2(relu) -> head
//   blend commutes into GEMM: sum_e c_e (x@W_e) = [c_e*x]_cat @ vstack(W_e)
// v2 structure: 1024 thr / 16 waves / 128 rows per block, A-operands held in
// registers (LDS stores activations in MFMA A-fragment layout), K-loop is
// t8-outer/e-inner (weights pre-permuted accordingly), ring-buffered
// global_load_lds staging with counted vmcnt (wait-before-barrier).
// ---------------------------------------------------------------------------

typedef _Float16 half8 __attribute__((ext_vector_type(8)));
typedef _Float16 half4v __attribute__((ext_vector_type(4)));
typedef float floatx4 __attribute__((ext_vector_type(4)));

#define MFMA16(a, b, c) __builtin_amdgcn_mfma_f32_16x16x32_f16(a, b, c, 0, 0, 0)
#define WAIT_VM(N) asm volatile("s_waitcnt vmcnt(" #N ")" ::: "memory")
#define WAIT_LGKM0 asm volatile("s_waitcnt lgkmcnt(0)" ::: "memory")

__device__ __forceinline__ void barrier_mem() {
  asm volatile("" ::: "memory");
  __builtin_amdgcn_s_barrier();
  asm volatile("" ::: "memory");
}

__device__ __forceinline__ half8 splat8(_Float16 v) {
  half8 r = {v, v, v, v, v, v, v, v};
  return r;
}

__device__ __forceinline__ half8 make_cfrag(half4v c, int l) {
  half8 cf = {(_Float16)0, (_Float16)0, (_Float16)0, (_Float16)0,
              (_Float16)0, (_Float16)0, (_Float16)0, (_Float16)0};
  if (l < 16) { cf[0] = c[0]; cf[1] = c[1]; cf[2] = c[2]; cf[3] = c[3]; }
  return cf;
}

// global -> LDS direct copy, 16B per lane. LDS dest wave-uniform (HW adds
// lane*16); global src per-lane (+ l*8 halfwords).
__device__ __forceinline__ void load_lds16(const _Float16* g, _Float16* s) {
  __builtin_amdgcn_global_load_lds((__attribute__((address_space(1))) void*)(g),
                                   (__attribute__((address_space(3))) void*)(s), 16, 0, 0);
}

// ---- d_ws halfword offsets (prepped f16 weights, fragment order) ----
// W1P/W2P tiles in CONSUMPTION order t: t8 = t>>2, e = t&3  (kstep = e*8+t8)
enum {
  W1P = 0,        // 32 tiles x [16 ct][64 l][8 j] = 262144
  W2P = 262144,   // 32 tiles x [ 8 ct][64 l][8 j] = 131072
  WMUP = 393216,  // 16 tiles x [ 2 ct][64 l][8 j] = 16384   (t2 = t>>2, e = t&3)
  GW1P = 409600,  //  8 tiles x [ 2 ct][64 l][8 j] = 8192
  GW2P = 417792,  //  1 tile  x [ 2 ct][64 l][8 j] = 1024
  GWOP = 418816,  //  [64 l][8 j] (cols 0-3 = gWo, rest 0) = 512
  B1P = 419328,   //  [16 ct][64][8], k<4 = b1 = 8192
  B2P = 427520,   //  [ 8 ct][64][8], k<4 = b2 = 4096
  BMUP = 431616,  //  [ 2 ct][64][8], k<4,o<17 = bmu = 1024
  WS_TOTAL = 432640
};

__global__ __launch_bounds__(256) void prep_kernel(
    const float* __restrict__ W1, const float* __restrict__ W2,
    const float* __restrict__ Wmu, const float* __restrict__ gW1,
    const float* __restrict__ gW2, const float* __restrict__ gWo,
    const float* __restrict__ b1, const float* __restrict__ b2,
    const float* __restrict__ bmu, _Float16* __restrict__ ws) {
  int p = blockIdx.x * 256 + threadIdx.x;
  if (p >= WS_TOTAL) return;
  float v = 0.f;
  if (p < W2P) {  // W1 region
    int t = p >> 13, r = p & 8191;
    int ct = r >> 9, l = (r >> 3) & 63, j = r & 7;
    int o = ct * 16 + (l & 15), krel = ((l >> 4) << 3) + j;
    int t8 = t >> 2, e = t & 3;
    v = W1[(e * 256 + t8 * 32 + krel) * 256 + o];
  } else if (p < WMUP) {  // W2 region
    int q = p - W2P, t = q >> 12, r = q & 4095;
    int ct = r >> 9, l = (r >> 3) & 63, j = r & 7;
    int o = ct * 16 + (l & 15), krel = ((l >> 4) << 3) + j;
    int t8 = t >> 2, e = t & 3;
    v = W2[(e * 256 + t8 * 32 + krel) * 128 + o];
  } else if (p < GW1P) {  // Wmu region (pad cols to 32)
    int q = p - WMUP, t = q >> 10, r = q & 1023;
    int ct = r >> 9, l = (r >> 3) & 63, j = r & 7;
    int o = ct * 16 + (l & 15), krel = ((l >> 4) << 3) + j;
    int t2 = t >> 2, e = t & 3;
    v = (o < 17) ? Wmu[(e * 128 + t2 * 32 + krel) * 17 + o] : 0.f;
  } else if (p < GW2P) {  // gW1 [256][32]
    int q = p - GW1P, ks = q >> 10, r = q & 1023;
    int ct = r >> 9, l = (r >> 3) & 63, j = r & 7;
    int o = ct * 16 + (l & 15), krel = ((l >> 4) << 3) + j;
    v = gW1[(ks * 32 + krel) * 32 + o];
  } else if (p < GWOP) {  // gW2 [32][32]
    int q = p - GW2P;
    int ct = q >> 9, l = (q >> 3) & 63, j = q & 7;
    int o = ct * 16 + (l & 15), krel = ((l >> 4) << 3) + j;
    v = gW2[krel * 32 + o];
  } else if (p < B1P) {  // gWo [32][4] padded to 16 cols
    int q = p - GWOP;
    int l = (q >> 3) & 63, j = q & 7;
    int o = l & 15, krel = ((l >> 4) << 3) + j;
    v = (o < 4) ? gWo[krel * 4 + o] : 0.f;
  } else if (p < B2P) {  // b1 [4][256]
    int q = p - B1P;
    int ct = q >> 9, l = (q >> 3) & 63, j = q & 7;
    int o = ct * 16 + (l & 15), krel = ((l >> 4) << 3) + j;
    v = (krel < 4) ? b1[krel * 256 + o] : 0.f;
  } else if (p < BMUP) {  // b2 [4][128]
    int q = p - B2P;
    int ct = q >> 9, l = (q >> 3) & 63, j = q & 7;
    int o = ct * 16 + (l & 15), krel = ((l >> 4) << 3) + j;
    v = (krel < 4) ? b2[krel * 128 + o] : 0.f;
  } else {  // bmu [4][17]
    int q = p - BMUP;
    int ct = q >> 9, l = (q >> 3) & 63, j = q & 7;
    int o = ct * 16 + (l & 15), krel = ((l >> 4) << 3) + j;
    v = (krel < 4 && o < 17) ? bmu[krel * 17 + o] : 0.f;
  }
  ws[p] = (_Float16)v;
}

// LDS map (halfwords):
//  [0,32768)        frag region: x-frags [8 t8][2 mr][4 rt][64 l][8 j]
//                   -> later h1-frags (same layout) -> later h2-frags (first 16K)
//  [32768,73728)    RING: 5 x 8192 (L1, 16KB tiles) == 10 x 4096 (L2, 8KB tiles)
//                   slots 3,4 double as gate area before L1 tiles 3,4 arrive
enum {
  RING = 32768,
  GATE = 57344,          // = RING + 3*8192 (slot 3): gW1p 8 tiles x 1024
  GW2L = GATE + 8192,    // slot 4 start: gW2p
  GWOL = GATE + 9216,
  BNC = GATE + 9728,     // 2 x 2048 scratch (per mr) for gate relayout
  CLDS = GATE + 13824,   // c [128][4] f16
  LDS_HW = 73728         // 144 KB
};

__global__ __launch_bounds__(1024, 4) void actor_kernel(
    const float* __restrict__ x, const _Float16* __restrict__ ws,
    const float* __restrict__ gb1, const float* __restrict__ gb2,
    const float* __restrict__ gbo, float* __restrict__ out) {
  __shared__ __align__(16) _Float16 lds[LDS_HW];
  const int tid = threadIdx.x;
  const int l = tid & 63;
  const int w = tid >> 6;
  const int l15 = l & 15;
  const int g8 = (l >> 4) << 3;
  const int mr = w >> 3;   // 2 row groups of 64
  const int nc = w & 7;    // 8 col strips
  const long rowbase = (long)blockIdx.x * 128;
  const int fragBase = mr * 2048 + l * 8;
  const floatx4 z4 = {0.f, 0.f, 0.f, 0.f};

  // ---------------- P0: x -> f16 A-frags (this wave fills t8 = nc) ----------
  {
    const float* xp = x + (rowbase + mr * 64) * 256 + nc * 32 + g8;
#pragma unroll
    for (int rt = 0; rt < 4; ++rt) {
      const float4* rp = (const float4*)(xp + (rt * 16 + l15) * 256);
      float4 v0 = rp[0], v1 = rp[1];
      half8 h = {(_Float16)v0.x, (_Float16)v0.y, (_Float16)v0.z, (_Float16)v0.w,
                 (_Float16)v1.x, (_Float16)v1.y, (_Float16)v1.z, (_Float16)v1.w};
      *(half8*)(&lds[nc * 4096 + fragBase + rt * 512]) = h;
    }
    for (int c = w; c < 19; c += 16)  // gate weights -> GATE..GWOL
      load_lds16(ws + GW1P + c * 512 + l * 8, lds + GATE + c * 512);
#pragma unroll
    for (int t = 0; t < 3; ++t)       // ring tiles 0..2 (0 = b1p)
      load_lds16(ws + (t == 0 ? B1P : W1P + (t - 1) * 8192) + w * 512 + l * 8,
                 lds + RING + t * 8192 + w * 512);
    WAIT_VM(3);   // gate weights landed; ring 0..2 in flight
    WAIT_LGKM0;
    barrier_mem();
  }

  // ---------------- gate (2 waves: nc==0, one per mr) -----------------------
  if (nc == 0) {
    floatx4 ga[4][2];
#pragma unroll
    for (int rt = 0; rt < 4; ++rt) { ga[rt][0] = z4; ga[rt][1] = z4; }
#pragma unroll
    for (int ks = 0; ks < 8; ++ks) {
      half8 b0 = *(const half8*)(&lds[GATE + ks * 1024 + l * 8]);
      half8 b1v = *(const half8*)(&lds[GATE + ks * 1024 + 512 + l * 8]);
#pragma unroll
      for (int rt = 0; rt < 4; ++rt) {
        half8 a = *(const half8*)(&lds[ks * 4096 + fragBase + rt * 512]);
        ga[rt][0] = MFMA16(a, b0, ga[rt][0]);
        ga[rt][1] = MFMA16(a, b1v, ga[rt][1]);
      }
    }
    // g1 = elu(ga + gb1) -> scatter into A-frag layout at BNC
#pragma unroll
    for (int rt = 0; rt < 4; ++rt)
#pragma unroll
      for (int ct = 0; ct < 2; ++ct) {
        const int c32 = ct * 16 + l15;
        const float bias = gb1[c32];
        const int hi4 = (c32 >> 3) << 4, jj = c32 & 7;
#pragma unroll
        for (int rg = 0; rg < 4; ++rg) {
          float vv = ga[rt][ct][rg] + bias;
          vv = vv > 0.f ? vv : (__expf(vv) - 1.f);
          const int lp = (4 * (l >> 4) + rg) | hi4;
          lds[BNC + mr * 2048 + rt * 512 + lp * 8 + jj] = (_Float16)vv;
        }
      }
    WAIT_LGKM0;
    // GEMM2: g2 = elu(g1 @ gW2 + gb2)
    floatx4 g2[4][2];
    {
      half8 bw0 = *(const half8*)(&lds[GW2L + l * 8]);
      half8 bw1 = *(const half8*)(&lds[GW2L + 512 + l * 8]);
#pragma unroll
      for (int rt = 0; rt < 4; ++rt) {
        half8 a = *(const half8*)(&lds[BNC + mr * 2048 + rt * 512 + l * 8]);
        g2[rt][0] = MFMA16(a, bw0, z4);
        g2[rt][1] = MFMA16(a, bw1, z4);
      }
    }
    WAIT_LGKM0;
#pragma unroll
    for (int rt = 0; rt < 4; ++rt)
#pragma unroll
      for (int ct = 0; ct < 2; ++ct) {
        const int c32 = ct * 16 + l15;
        const float bias = gb2[c32];
        const int hi4 = (c32 >> 3) << 4, jj = c32 & 7;
#pragma unroll
        for (int rg = 0; rg < 4; ++rg) {
          float vv = g2[rt][ct][rg] + bias;
          vv = vv > 0.f ? vv : (__expf(vv) - 1.f);
          const int lp = (4 * (l >> 4) + rg) | hi4;
          lds[BNC + mr * 2048 + rt * 512 + lp * 8 + jj] = (_Float16)vv;
        }
      }
    WAIT_LGKM0;
    // logits + softmax -> CLDS
    {
      half8 bo = *(const half8*)(&lds[GWOL + l * 8]);
      const float bze = (l15 < 4) ? gbo[l15] : 0.f;
#pragma unroll
      for (int rt = 0; rt < 4; ++rt) {
        half8 a = *(const half8*)(&lds[BNC + mr * 2048 + rt * 512 + l * 8]);
        floatx4 lg = MFMA16(a, bo, z4);
#pragma unroll
        for (int rg = 0; rg < 4; ++rg) {
          float vv = lg[rg] + bze;
          float m = fmaxf(vv, __shfl_xor(vv, 1));
          m = fmaxf(m, __shfl_xor(m, 2));
          float eo = __expf(vv - m);
          float sden = eo + __shfl_xor(eo, 1);
          sden = sden + __shfl_xor(sden, 2);
          float c = eo / sden;
          if (l15 < 4)
            lds[CLDS + (mr * 64 + rt * 16 + 4 * (l >> 4) + rg) * 4 + l15] = (_Float16)c;
        }
      }
    }
    WAIT_LGKM0;
  }
  barrier_mem();

  // ---------------- all waves: read coefficients; issue ring tile 3 ---------
  half4v c4[4];
#pragma unroll
  for (int rt = 0; rt < 4; ++rt)
    c4[rt] = *(const half4v*)(&lds[CLDS + (mr * 64 + rt * 16 + l15) * 4]);
  load_lds16(ws + W1P + 2 * 8192 + w * 512 + l * 8, lds + RING + 3 * 8192 + w * 512);
  WAIT_VM(3);    // tile 0 (b1p) landed
  WAIT_LGKM0;    // c4 in regs before slot-4 tile can be issued by anyone
  barrier_mem();

  // ---------------- L1 bias phase (tile 0), issue tile 4 --------------------
  floatx4 acc[4][2];
  const int bBase = nc * 1024 + l * 8;
  load_lds16(ws + W1P + 3 * 8192 + w * 512 + l * 8, lds + RING + 4 * 8192 + w * 512);
  {
    half8 b0 = *(const half8*)(&lds[RING + bBase]);
    half8 b1v = *(const half8*)(&lds[RING + bBase + 512]);
#pragma unroll
    for (int rt = 0; rt < 4; ++rt) {
      half8 cfr = make_cfrag(c4[rt], l);
      acc[rt][0] = MFMA16(cfr, b0, z4);
      acc[rt][1] = MFMA16(cfr, b1v, z4);
    }
  }
  WAIT_VM(3);  // tile 1 landed
  barrier_mem();

  // ---------------- L1 main: t8-outer / e-inner, 5-slot ring ----------------
  half8 af[4];
  int s = 1, sp = 0;  // read slot (t%5), issue slot ((t+4)%5 == (t-1)%5)
#pragma unroll 1
  for (int t8 = 0; t8 < 8; ++t8) {
#pragma unroll
    for (int e = 0; e < 4; ++e) {
      const int t = t8 * 4 + e + 1;
      if (t8 < 7)
        load_lds16(ws + W1P + (t + 3) * 8192 + w * 512 + l * 8,
                   lds + RING + sp * 8192 + w * 512);
      if (e == 0) {
#pragma unroll
        for (int rt = 0; rt < 4; ++rt)
          af[rt] = *(const half8*)(&lds[t8 * 4096 + fragBase + rt * 512]);
      }
      const int slot = RING + s * 8192;
      half8 b0 = *(const half8*)(&lds[slot + bBase]);
      half8 b1v = *(const half8*)(&lds[slot + bBase + 512]);
#pragma unroll
      for (int rt = 0; rt < 4; ++rt) {
        half8 as = af[rt] * splat8(c4[rt][e]);
        acc[rt][0] = MFMA16(as, b0, acc[rt][0]);
        acc[rt][1] = MFMA16(as, b1v, acc[rt][1]);
      }
      if (t8 < 7) { WAIT_VM(3); }
      else if (e == 0) { WAIT_VM(2); }
      else if (e == 1) { WAIT_VM(1); }
      else if (e == 2) { WAIT_VM(0); }
      barrier_mem();
      sp = s;
      s = (s == 4) ? 0 : s + 1;
    }
  }

  // ---------------- h1 = relu(acc) -> frags; L2 ring prologue ---------------
#pragma unroll
  for (int rt = 0; rt < 4; ++rt)
#pragma unroll
    for (int ct = 0; ct < 2; ++ct) {
      const int c32 = ct * 16 + l15;
      const int hi4 = (c32 >> 3) << 4, jj = c32 & 7;
#pragma unroll
      for (int rg = 0; rg < 4; ++rg) {
        float vv = acc[rt][ct][rg];
        vv = vv > 0.f ? vv : 0.f;
        const int lp = (4 * (l >> 4) + rg) | hi4;
        lds[nc * 4096 + mr * 2048 + rt * 512 + lp * 8 + jj] = (_Float16)vv;
      }
    }
  if (w < 8) {
#pragma unroll
    for (int t = 0; t < 8; ++t)  // L2 tiles 0..7 (0 = b2p), 8KB each
      load_lds16(ws + (t == 0 ? B2P : W2P + (t - 1) * 4096) + w * 512 + l * 8,
                 lds + RING + t * 4096 + w * 512);
  }
  WAIT_LGKM0;
  if (w < 8) { WAIT_VM(7); }
  barrier_mem();

  // ---------------- L2 bias phase, issue tile 8 -----------------------------
  floatx4 acc2[4];
  const int b2B = nc * 512 + l * 8;
  if (w < 8)
    load_lds16(ws + W2P + 7 * 4096 + w * 512 + l * 8, lds + RING + 8 * 4096 + w * 512);
  {
    half8 b0 = *(const half8*)(&lds[RING + b2B]);
#pragma unroll
    for (int rt = 0; rt < 4; ++rt) {
      half8 cfr = make_cfrag(c4[rt], l);
      acc2[rt] = MFMA16(cfr, b0, z4);
    }
  }
  if (w < 8) { WAIT_VM(7); }
  barrier_mem();

  // ---------------- L2 main: 10-slot ring, window 8 -------------------------
  int su = 1;
#pragma unroll 1
  for (int t8 = 0; t8 < 8; ++t8) {
#pragma unroll
    for (int e = 0; e < 4; ++e) {
      const int t = t8 * 4 + e + 1;
      if (t8 < 6 && w < 8) {
        const int si = (su >= 2) ? su - 2 : su + 8;  // (t+8)%10
        load_lds16(ws + W2P + (t + 7) * 4096 + w * 512 + l * 8,
                   lds + RING + si * 4096 + w * 512);
      }
      if (e == 0) {
#pragma unroll
        for (int rt = 0; rt < 4; ++rt)
          af[rt] = *(const half8*)(&lds[t8 * 4096 + fragBase + rt * 512]);
      }
      half8 b0 = *(const half8*)(&lds[RING + su * 4096 + b2B]);
#pragma unroll
      for (int rt = 0; rt < 4; ++rt) {
        half8 as = af[rt] * splat8(c4[rt][e]);
        acc2[rt] = MFMA16(as, b0, acc2[rt]);
      }
      if (w < 8) {
        if (t8 < 6) { WAIT_VM(7); }
        else if (t8 == 6) {
          if (e == 0) { WAIT_VM(6); } else if (e == 1) { WAIT_VM(5); }
          else if (e == 2) { WAIT_VM(4); } else { WAIT_VM(3); }
        } else {
          if (e == 0) { WAIT_VM(2); } else if (e == 1) { WAIT_VM(1); }
          else if (e == 2) { WAIT_VM(0); }
        }
      }
      barrier_mem();
      su = (su == 9) ? 0 : su + 1;
    }
  }

  // ---------------- h2 = relu(acc2) -> frags; stage head tiles --------------
  {
    const int c32 = ((nc & 1) << 4) | l15;
    const int hi4 = (c32 >> 3) << 4, jj = c32 & 7;
    const int hb = (nc >> 1) * 4096 + mr * 2048;
#pragma unroll
    for (int rt = 0; rt < 4; ++rt)
#pragma unroll
      for (int rg = 0; rg < 4; ++rg) {
        float vv = acc2[rt][rg];
        vv = vv > 0.f ? vv : 0.f;
        const int lp = (4 * (l >> 4) + rg) | hi4;
        lds[hb + rt * 512 + lp * 8 + jj] = (_Float16)vv;
      }
  }
  for (int c = w; c < 34; c += 16) {  // [bmup 2][16 Wmu tiles x 2] chunks
    const _Float16* src = (c < 2) ? (ws + BMUP + c * 512) : (ws + WMUP + (c - 2) * 512);
    load_lds16(src + l * 8, lds + RING + c * 512);
  }
  WAIT_LGKM0;
  WAIT_VM(0);
  barrier_mem();

  // ---------------- head (waves nc<2): [128,512]@[512,32pad] ----------------
  if (nc < 2) {
    floatx4 hd[4];
    const int hB = nc * 512 + l * 8;
    {
      half8 bb = *(const half8*)(&lds[RING + hB]);
#pragma unroll
      for (int rt = 0; rt < 4; ++rt) {
        half8 cfr = make_cfrag(c4[rt], l);
        hd[rt] = MFMA16(cfr, bb, z4);
      }
    }
#pragma unroll
    for (int t2 = 0; t2 < 4; ++t2) {
      half8 ah[4];
#pragma unroll
      for (int rt = 0; rt < 4; ++rt)
        ah[rt] = *(const half8*)(&lds[(t2 * 2 + mr) * 2048 + rt * 512 + l * 8]);
#pragma unroll
      for (int e = 0; e < 4; ++e) {
        half8 bh = *(const half8*)(&lds[RING + 1024 + (t2 * 4 + e) * 1024 + hB]);
#pragma unroll
        for (int rt = 0; rt < 4; ++rt) {
          half8 as = ah[rt] * splat8(c4[rt][e]);
          hd[rt] = MFMA16(as, bh, hd[rt]);
        }
      }
    }
    const int col = nc * 16 + l15;
    if (col < 17) {
#pragma unroll
      for (int rt = 0; rt < 4; ++rt)
#pragma unroll
        for (int rg = 0; rg < 4; ++rg)
          out[(rowbase + mr * 64 + rt * 16 + 4 * (l >> 4) + rg) * 17 + col] = hd[rt][rg];
    }
  }
}

extern "C" void kernel_launch(void* const* d_in, const int* in_sizes, int n_in,
                              void* d_out, int out_size, void* d_ws, size_t ws_size,
                              hipStream_t stream) {
  const float* x = (const float*)d_in[0];
  const float* W1 = (const float*)d_in[1];
  const float* b1 = (const float*)d_in[2];
  const float* W2 = (const float*)d_in[3];
  const float* b2 = (const float*)d_in[4];
  const float* Wmu = (const float*)d_in[5];
  const float* bmu = (const float*)d_in[6];
  const float* gW1 = (const float*)d_in[7];
  const float* gb1 = (const float*)d_in[8];
  const float* gW2 = (const float*)d_in[9];
  const float* gb2 = (const float*)d_in[10];
  const float* gWo = (const float*)d_in[11];
  const float* gbo = (const float*)d_in[12];
  float* out = (float*)d_out;
  _Float16* ws = (_Float16*)d_ws;

  prep_kernel<<<(WS_TOTAL + 255) / 256, 256, 0, stream>>>(W1, W2, Wmu, gW1, gW2, gWo,
                                                          b1, b2, bmu, ws);
  actor_kernel<<<1024, 1024, 0, stream>>>(x, ws, gb1, gb2, gbo, out);
}

// Round 4
// 372.505 us; speedup vs baseline: 3.0573x; 3.0573x over previous
//
#include <hip/hip_runtime.h>

// ---------------------------------------------------------------------------
// Fused 4-expert MoE actor:  gate(softmax) -> L1(relu) -> L2(relu) -> head
//   blend commutes into GEMM: sum_e c_e (x@W_e) = [c_e*x]_cat @ vstack(W_e)
// v3b: 512 thr / 8 waves / 64 rows / 2048 blocks; LDS = exactly 80 KB so
// 2 blocks/CU co-reside. A-operands in registers (activations in MFMA A-frag
// layout in LDS, read once per 4 experts); weights stream via global_load_lds
// rings (ring-3 of 16KB for L1, ring-6 of 8KB for L2) with counted vmcnt.
// RULE: every wave waits its own vmcnt BEFORE a barrier whose consumers are
// cross-wave (v3 bug: gate chunks waited after the barrier -> race).
// ---------------------------------------------------------------------------

typedef _Float16 half8 __attribute__((ext_vector_type(8)));
typedef _Float16 half4v __attribute__((ext_vector_type(4)));
typedef float floatx4 __attribute__((ext_vector_type(4)));

#define MFMA16(a, b, c) __builtin_amdgcn_mfma_f32_16x16x32_f16(a, b, c, 0, 0, 0)
#define WAIT_VM(N) asm volatile("s_waitcnt vmcnt(" #N ")" ::: "memory")
#define WAIT_LGKM0 asm volatile("s_waitcnt lgkmcnt(0)" ::: "memory")

__device__ __forceinline__ void barrier_mem() {
  asm volatile("" ::: "memory");
  __builtin_amdgcn_s_barrier();
  asm volatile("" ::: "memory");
}

__device__ __forceinline__ half8 splat8(_Float16 v) {
  half8 r = {v, v, v, v, v, v, v, v};
  return r;
}

// coeff A-fragment for the K=32 bias tile: B rows k>=4 are zero by prep, so
// garbage in A cols k>=8 (lanes 16+) is harmless; cols 4..7 are zeroed here.
__device__ __forceinline__ half8 make_cfrag(half4v c) {
  half8 r = {c[0], c[1], c[2], c[3], (_Float16)0, (_Float16)0, (_Float16)0, (_Float16)0};
  return r;
}

// global -> LDS direct copy, 16B/lane. LDS dest must be wave-uniform
// (HW adds lane*16); global src is per-lane (+ l*8 halfwords).
__device__ __forceinline__ void load_lds16(const _Float16* g, _Float16* s) {
  __builtin_amdgcn_global_load_lds((__attribute__((address_space(1))) void*)(g),
                                   (__attribute__((address_space(3))) void*)(s), 16, 0, 0);
}

// ---- d_ws halfword offsets (prepped f16 weights, fragment order) ----
// W1P/W2P/WMUP tiles in CONSUMPTION order t: t8 = t>>2, e = t&3 (kstep = e*8+t8)
enum {
  W1P = 0,        // 32 tiles x [16 ct][64 l][8 j] = 262144
  W2P = 262144,   // 32 tiles x [ 8 ct][64 l][8 j] = 131072
  WMUP = 393216,  // 16 tiles x [ 2 ct][64 l][8 j] = 16384
  GW1P = 409600,  //  8 tiles x [ 2 ct][64 l][8 j] = 8192
  GW2P = 417792,  //  1 tile  x [ 2 ct][64 l][8 j] = 1024
  GWOP = 418816,  //  [64 l][8 j] (cols 0-3 = gWo, rest 0) = 512
  B1P = 419328,   //  [16 ct][64][8], k<4 = b1 = 8192
  B2P = 427520,   //  [ 8 ct][64][8], k<4 = b2 = 4096
  BMUP = 431616,  //  [ 2 ct][64][8], k<4,o<17 = bmu = 1024
  GBIASP = 432640,//  [0..31]=gb1 [32..63]=gb2 [64..67]=gbo, pad = 512
  WS_TOTAL = 433152
};

__global__ __launch_bounds__(256) void prep_kernel(
    const float* __restrict__ W1, const float* __restrict__ W2,
    const float* __restrict__ Wmu, const float* __restrict__ gW1,
    const float* __restrict__ gW2, const float* __restrict__ gWo,
    const float* __restrict__ b1, const float* __restrict__ b2,
    const float* __restrict__ bmu, const float* __restrict__ gb1,
    const float* __restrict__ gb2, const float* __restrict__ gbo,
    _Float16* __restrict__ ws) {
  int p = blockIdx.x * 256 + threadIdx.x;
  if (p >= WS_TOTAL) return;
  float v = 0.f;
  if (p < W2P) {  // W1 stacked [1024 k][256 o]
    int t = p >> 13, r = p & 8191;
    int ct = r >> 9, l = (r >> 3) & 63, j = r & 7;
    int o = ct * 16 + (l & 15), krel = ((l >> 4) << 3) + j;
    int t8 = t >> 2, e = t & 3;
    v = W1[(e * 256 + t8 * 32 + krel) * 256 + o];
  } else if (p < WMUP) {  // W2 stacked [1024 k][128 o]
    int q = p - W2P, t = q >> 12, r = q & 4095;
    int ct = r >> 9, l = (r >> 3) & 63, j = r & 7;
    int o = ct * 16 + (l & 15), krel = ((l >> 4) << 3) + j;
    int t8 = t >> 2, e = t & 3;
    v = W2[(e * 256 + t8 * 32 + krel) * 128 + o];
  } else if (p < GW1P) {  // Wmu stacked [512 k][17 o] padded to 32 cols
    int q = p - WMUP, t = q >> 10, r = q & 1023;
    int ct = r >> 9, l = (r >> 3) & 63, j = r & 7;
    int o = ct * 16 + (l & 15), krel = ((l >> 4) << 3) + j;
    int t2 = t >> 2, e = t & 3;
    v = (o < 17) ? Wmu[(e * 128 + t2 * 32 + krel) * 17 + o] : 0.f;
  } else if (p < GW2P) {  // gW1 [256][32]
    int q = p - GW1P, ks = q >> 10, r = q & 1023;
    int ct = r >> 9, l = (r >> 3) & 63, j = r & 7;
    int o = ct * 16 + (l & 15), krel = ((l >> 4) << 3) + j;
    v = gW1[(ks * 32 + krel) * 32 + o];
  } else if (p < GWOP) {  // gW2 [32][32]
    int q = p - GW2P;
    int ct = q >> 9, l = (q >> 3) & 63, j = q & 7;
    int o = ct * 16 + (l & 15), krel = ((l >> 4) << 3) + j;
    v = gW2[krel * 32 + o];
  } else if (p < B1P) {  // gWo [32][4] padded to 16 cols
    int q = p - GWOP;
    int l = (q >> 3) & 63, j = q & 7;
    int o = l & 15, krel = ((l >> 4) << 3) + j;
    v = (o < 4) ? gWo[krel * 4 + o] : 0.f;
  } else if (p < B2P) {  // b1 [4][256]
    int q = p - B1P;
    int ct = q >> 9, l = (q >> 3) & 63, j = q & 7;
    int o = ct * 16 + (l & 15), krel = ((l >> 4) << 3) + j;
    v = (krel < 4) ? b1[krel * 256 + o] : 0.f;
  } else if (p < BMUP) {  // b2 [4][128]
    int q = p - B2P;
    int ct = q >> 9, l = (q >> 3) & 63, j = q & 7;
    int o = ct * 16 + (l & 15), krel = ((l >> 4) << 3) + j;
    v = (krel < 4) ? b2[krel * 128 + o] : 0.f;
  } else if (p < GBIASP) {  // bmu [4][17]
    int q = p - BMUP;
    int ct = q >> 9, l = (q >> 3) & 63, j = q & 7;
    int o = ct * 16 + (l & 15), krel = ((l >> 4) << 3) + j;
    v = (krel < 4 && o < 17) ? bmu[krel * 17 + o] : 0.f;
  } else {  // gate biases
    int q = p - GBIASP;
    v = (q < 32) ? gb1[q] : (q < 64) ? gb2[q - 32] : (q < 68) ? gbo[q - 64] : 0.f;
  }
  ws[p] = (_Float16)v;
}

// LDS map (halfwords), total 40960 hw = 81920 B -> exactly 2 blocks/CU.
//  FRAG [0,16384):  activation A-frags [8 t8][4 rt][64 l][8 j]
//                   (x, then h1 same layout, then h2 in first 4 chunks)
//  STG  [16384,40960): 48 KB staging = ring-3 x 16KB (L1) / ring-6 x 8KB (L2)
//                   / 17 x 2KB tiles (head); gate overlays during gate phase.
enum {
  STG = 16384,
  GW2L = STG + 8192,   // gate: slot B start
  GWOL = STG + 9216,
  GBL = STG + 9728,    // gb1@+0 gb2@+32 gbo@+64 (f16)
  SCR1 = STG + 10240,  // gate g1 frags [4 rt][64][8]
  SCR2 = STG + 12288,  // gate g2 frags
  COEF = STG + 14336,  // c [64 rows][4 e] f16
  LDS_HW = 40960
};
static_assert(LDS_HW * 2 == 81920, "LDS must be exactly 80KB");

__global__ __launch_bounds__(512, 2) void actor_kernel(
    const float* __restrict__ x, const _Float16* __restrict__ ws,
    float* __restrict__ out) {
  __shared__ __align__(16) _Float16 lds[LDS_HW];
  const int tid = threadIdx.x;
  const int l = tid & 63;
  const int w = tid >> 6;       // wave 0..7 == N-strip (32 cols L1, 16 cols L2)
  const int l15 = l & 15;
  const int g8 = (l >> 4) << 3;
  const long rowbase = (long)blockIdx.x * 64;
  const floatx4 z4 = {0.f, 0.f, 0.f, 0.f};

  // ---------------- P0: x -> f16 A-frags (wave fills chunk t8 = w) ----------
  {
    const float* xp = x + rowbase * 256 + w * 32 + g8;
#pragma unroll
    for (int rt = 0; rt < 4; ++rt) {
      const float* rr = xp + (rt * 16 + l15) * 256;
      float4 v0 = *(const float4*)rr;
      float4 v1 = *(const float4*)(rr + 4);
      half8 h = {(_Float16)v0.x, (_Float16)v0.y, (_Float16)v0.z, (_Float16)v0.w,
                 (_Float16)v1.x, (_Float16)v1.y, (_Float16)v1.z, (_Float16)v1.w};
      *(half8*)(&lds[w * 2048 + rt * 512 + l * 8]) = h;
    }
  }
  // gate weight chunks (20 x 1KB) + T0 (b1p -> slot C)
  for (int c = w; c < 20; c += 8) {
    const _Float16* src;
    _Float16* dst;
    if (c < 16) { src = ws + GW1P + c * 512; dst = lds + STG + c * 512; }
    else if (c < 18) { src = ws + GW2P + (c - 16) * 512; dst = lds + GW2L + (c - 16) * 512; }
    else if (c == 18) { src = ws + GWOP; dst = lds + GWOL; }
    else { src = ws + GBIASP; dst = lds + GBL; }
    load_lds16(src + l * 8, dst);
  }
  load_lds16(ws + B1P + w * 512 + l * 8, lds + STG + 16384 + w * 512);
  load_lds16(ws + B1P + (w + 8) * 512 + l * 8, lds + STG + 16384 + (w + 8) * 512);
  WAIT_LGKM0;
  WAIT_VM(2);  // own gate chunks landed BEFORE barrier (b1p x2 stay in flight)
  barrier_mem();

  // ---------------- gate stage A: g1 = elu(x@gW1+gb1), all 8 waves ----------
  const int grt = w & 3, gct = w >> 2;
  {
    floatx4 ga = z4;
#pragma unroll
    for (int ks = 0; ks < 8; ++ks) {
      half8 a = *(const half8*)(&lds[ks * 2048 + grt * 512 + l * 8]);
      half8 b = *(const half8*)(&lds[STG + ks * 1024 + gct * 512 + l * 8]);
      ga = MFMA16(a, b, ga);
    }
    const int col = gct * 16 + l15;
    const float bias = (float)lds[GBL + col];
    const int hi4 = ((col >> 3) & 3) << 4, jj = col & 7;
#pragma unroll
    for (int rg = 0; rg < 4; ++rg) {
      float v = ga[rg] + bias;
      v = v > 0.f ? v : (__expf(v) - 1.f);
      lds[SCR1 + grt * 512 + ((4 * (l >> 4) + rg) | hi4) * 8 + jj] = (_Float16)v;
    }
  }
  WAIT_LGKM0;
  barrier_mem();

  // ---------------- gate stage B: g2 = elu(g1@gW2+gb2) ----------------------
  {
    half8 a = *(const half8*)(&lds[SCR1 + grt * 512 + l * 8]);
    half8 b = *(const half8*)(&lds[GW2L + gct * 512 + l * 8]);
    floatx4 g2 = MFMA16(a, b, z4);
    const int col = gct * 16 + l15;
    const float bias = (float)lds[GBL + 32 + col];
    const int hi4 = ((col >> 3) & 3) << 4, jj = col & 7;
#pragma unroll
    for (int rg = 0; rg < 4; ++rg) {
      float v = g2[rg] + bias;
      v = v > 0.f ? v : (__expf(v) - 1.f);
      lds[SCR2 + grt * 512 + ((4 * (l >> 4) + rg) | hi4) * 8 + jj] = (_Float16)v;
    }
  }
  WAIT_LGKM0;
  barrier_mem();

  // ---------------- gate stage C: logits + softmax -> COEF (waves 0-3) ------
  if (gct == 0) {
    half8 a = *(const half8*)(&lds[SCR2 + grt * 512 + l * 8]);
    half8 bo = *(const half8*)(&lds[GWOL + l * 8]);
    floatx4 lg = MFMA16(a, bo, z4);
    const float bze = (l15 < 4) ? (float)lds[GBL + 64 + l15] : 0.f;
#pragma unroll
    for (int rg = 0; rg < 4; ++rg) {
      float v = lg[rg] + bze;
      float m = fmaxf(v, __shfl_xor(v, 1));
      m = fmaxf(m, __shfl_xor(m, 2));
      float eo = __expf(v - m);
      float sden = eo + __shfl_xor(eo, 1);
      sden += __shfl_xor(sden, 2);
      if (l15 < 4)
        lds[COEF + (grt * 16 + 4 * (l >> 4) + rg) * 4 + l15] = (_Float16)(eo / sden);
    }
  }
  WAIT_LGKM0;
  barrier_mem();

  // ---------------- coeff regs + issue T1 (W1 idx0 -> slot A) ---------------
  half4v c4[4];
#pragma unroll
  for (int rt = 0; rt < 4; ++rt)
    c4[rt] = *(const half4v*)(&lds[COEF + (rt * 16 + l15) * 4]);
  load_lds16(ws + W1P + w * 512 + l * 8, lds + STG + w * 512);
  load_lds16(ws + W1P + (w + 8) * 512 + l * 8, lds + STG + (w + 8) * 512);
  WAIT_VM(2);   // T0 landed
  WAIT_LGKM0;   // c4 in regs before COEF region is recycled
  barrier_mem();

  // ---------------- L1 phase 0: bias MFMA from T0 (slot C) ------------------
  floatx4 acc[4][2];
  {
    load_lds16(ws + W1P + 8192 + w * 512 + l * 8, lds + STG + 8192 + w * 512);         // T2 -> B
    load_lds16(ws + W1P + 8192 + (w + 8) * 512 + l * 8, lds + STG + 8192 + (w + 8) * 512);
    half8 b0 = *(const half8*)(&lds[STG + 16384 + w * 1024 + l * 8]);
    half8 b1v = *(const half8*)(&lds[STG + 16384 + w * 1024 + 512 + l * 8]);
#pragma unroll
    for (int rt = 0; rt < 4; ++rt) {
      half8 cf = make_cfrag(c4[rt]);
      acc[rt][0] = MFMA16(cf, b0, z4);
      acc[rt][1] = MFMA16(cf, b1v, z4);
    }
    WAIT_VM(2);  // T1 landed
    barrier_mem();
  }

  // ---------------- L1 main: T=1..32, ring-3, one barrier/phase -------------
  half8 af[4];
  int rs = 0;  // read slot for T; slot(T) = (T+2)%3
#pragma unroll 1
  for (int t8 = 0; t8 < 8; ++t8) {
#pragma unroll
    for (int e = 0; e < 4; ++e) {
      const int T = t8 * 4 + e + 1;
      if (T <= 30) {  // issue tile T+2 (W1 idx T+1) -> slot (rs+2)%3
        const int is3 = (rs >= 1) ? rs - 1 : 2;
        const _Float16* src = ws + W1P + (T + 1) * 8192 + l * 8;
        _Float16* dst = lds + STG + is3 * 8192;
        load_lds16(src + w * 512, dst + w * 512);
        load_lds16(src + (w + 8) * 512, dst + (w + 8) * 512);
      }
      if (e == 0) {
#pragma unroll
        for (int rt = 0; rt < 4; ++rt)
          af[rt] = *(const half8*)(&lds[t8 * 2048 + rt * 512 + l * 8]);
      }
      half8 b0 = *(const half8*)(&lds[STG + rs * 8192 + w * 1024 + l * 8]);
      half8 b1v = *(const half8*)(&lds[STG + rs * 8192 + w * 1024 + 512 + l * 8]);
#pragma unroll
      for (int rt = 0; rt < 4; ++rt) {
        half8 as = af[rt] * splat8(c4[rt][e]);
        acc[rt][0] = MFMA16(as, b0, acc[rt][0]);
        acc[rt][1] = MFMA16(as, b1v, acc[rt][1]);
      }
      if (T <= 30) { WAIT_VM(2); }
      else if (T == 31) { WAIT_VM(0); }
      barrier_mem();
      rs = (rs >= 2) ? 0 : rs + 1;
    }
  }

  // ---------------- h1 = relu(acc) -> frag chunk w; L2 prologue -------------
#pragma unroll
  for (int rt = 0; rt < 4; ++rt)
#pragma unroll
    for (int ct = 0; ct < 2; ++ct) {
      const int c32 = ct * 16 + l15;
      const int hi4 = ((c32 >> 3) & 3) << 4, jj = c32 & 7;
#pragma unroll
      for (int rg = 0; rg < 4; ++rg) {
        float v = acc[rt][ct][rg];
        v = v > 0.f ? v : 0.f;
        lds[w * 2048 + rt * 512 + ((4 * (l >> 4) + rg) | hi4) * 8 + jj] = (_Float16)v;
      }
    }
  // issue L2 T0..T3 -> sub-slots 4,5,0,1  (s6(T) = (T+4)%6)
  load_lds16(ws + B2P + w * 512 + l * 8, lds + STG + 4 * 4096 + w * 512);
  load_lds16(ws + W2P + 0 * 4096 + w * 512 + l * 8, lds + STG + 5 * 4096 + w * 512);
  load_lds16(ws + W2P + 1 * 4096 + w * 512 + l * 8, lds + STG + 0 * 4096 + w * 512);
  load_lds16(ws + W2P + 2 * 4096 + w * 512 + l * 8, lds + STG + 1 * 4096 + w * 512);
  WAIT_LGKM0;
  WAIT_VM(3);  // T0 landed
  barrier_mem();

  // ---------------- L2 phase 0: bias MFMA (sub-slot 4) ----------------------
  floatx4 acc2[4];
  {
    load_lds16(ws + W2P + 3 * 4096 + w * 512 + l * 8, lds + STG + 2 * 4096 + w * 512);  // T4
    half8 b0 = *(const half8*)(&lds[STG + 4 * 4096 + w * 512 + l * 8]);
#pragma unroll
    for (int rt = 0; rt < 4; ++rt) {
      half8 cf = make_cfrag(c4[rt]);
      acc2[rt] = MFMA16(cf, b0, z4);
    }
    WAIT_VM(3);  // T1 landed
    barrier_mem();
  }

  // ---------------- L2 main: T=1..32, ring-6, one barrier/phase -------------
  int rs6 = 5, is6 = 3;  // read slot (T+4)%6; issue slot (T+2)%6
#pragma unroll 1
  for (int t8 = 0; t8 < 8; ++t8) {
#pragma unroll
    for (int e = 0; e < 4; ++e) {
      const int T = t8 * 4 + e + 1;
      if (T <= 28)  // issue tile T+4 (W2 idx T+3)
        load_lds16(ws + W2P + (T + 3) * 4096 + w * 512 + l * 8,
                   lds + STG + is6 * 4096 + w * 512);
      if (e == 0) {
#pragma unroll
        for (int rt = 0; rt < 4; ++rt)
          af[rt] = *(const half8*)(&lds[t8 * 2048 + rt * 512 + l * 8]);
      }
      half8 b0 = *(const half8*)(&lds[STG + rs6 * 4096 + w * 512 + l * 8]);
#pragma unroll
      for (int rt = 0; rt < 4; ++rt) {
        half8 as = af[rt] * splat8(c4[rt][e]);
        acc2[rt] = MFMA16(as, b0, acc2[rt]);
      }
      if (T <= 28) { WAIT_VM(3); }
      else if (T == 29) { WAIT_VM(2); }
      else if (T == 30) { WAIT_VM(1); }
      else if (T == 31) { WAIT_VM(0); }
      barrier_mem();
      rs6 = (rs6 >= 5) ? 0 : rs6 + 1;
      is6 = (is6 >= 5) ? 0 : is6 + 1;
    }
  }

  // ---------------- h2 = relu(acc2) -> frag chunks 0..3; stage head ---------
  {
    const int c32 = ((w & 1) << 4) | l15;
    const int hi4 = ((c32 >> 3) & 3) << 4, jj = c32 & 7;
#pragma unroll
    for (int rt = 0; rt < 4; ++rt)
#pragma unroll
      for (int rg = 0; rg < 4; ++rg) {
        float v = acc2[rt][rg];
        v = v > 0.f ? v : 0.f;
        lds[(w >> 1) * 2048 + rt * 512 + ((4 * (l >> 4) + rg) | hi4) * 8 + jj] = (_Float16)v;
      }
  }
  for (int c = w; c < 34; c += 8) {  // T0=bmup (2 chunks) + 16 Wmu tiles
    const _Float16* src = (c < 2) ? (ws + BMUP + c * 512) : (ws + WMUP + (c - 2) * 512);
    load_lds16(src + l * 8, lds + STG + c * 512);
  }
  WAIT_LGKM0;
  WAIT_VM(0);
  barrier_mem();

  // ---------------- head: [64,512]@[512,32pad], all 8 waves -----------------
  {
    const int hrt = w & 3, hct = w >> 2;
    half8 cf = make_cfrag(c4[hrt]);
    half8 b = *(const half8*)(&lds[STG + hct * 512 + l * 8]);
    floatx4 hacc = MFMA16(cf, b, z4);
    half8 ah;
#pragma unroll
    for (int t = 0; t < 16; ++t) {
      if ((t & 3) == 0)
        ah = *(const half8*)(&lds[(t >> 2) * 2048 + hrt * 512 + l * 8]);
      half8 as = ah * splat8(c4[hrt][t & 3]);
      half8 bh = *(const half8*)(&lds[STG + (t + 1) * 1024 + hct * 512 + l * 8]);
      hacc = MFMA16(as, bh, hacc);
    }
    const int col = hct * 16 + l15;
    if (col < 17) {
#pragma unroll
      for (int rg = 0; rg < 4; ++rg)
        out[(rowbase + hrt * 16 + 4 * (l >> 4) + rg) * 17 + col] = hacc[rg];
    }
  }
}

extern "C" void kernel_launch(void* const* d_in, const int* in_sizes, int n_in,
                              void* d_out, int out_size, void* d_ws, size_t ws_size,
                              hipStream_t stream) {
  const float* x = (const float*)d_in[0];
  const float* W1 = (const float*)d_in[1];
  const float* b1 = (const float*)d_in[2];
  const float* W2 = (const float*)d_in[3];
  const float* b2 = (const float*)d_in[4];
  const float* Wmu = (const float*)d_in[5];
  const float* bmu = (const float*)d_in[6];
  const float* gW1 = (const float*)d_in[7];
  const float* gb1 = (const float*)d_in[8];
  const float* gW2 = (const float*)d_in[9];
  const float* gb2 = (const float*)d_in[10];
  const float* gWo = (const float*)d_in[11];
  const float* gbo = (const float*)d_in[12];
  float* out = (float*)d_out;
  _Float16* ws = (_Float16*)d_ws;

  prep_kernel<<<(WS_TOTAL + 255) / 256, 256, 0, stream>>>(
      W1, W2, Wmu, gW1, gW2, gWo, b1, b2, bmu, gb1, gb2, gbo, ws);
  actor_kernel<<<2048, 512, 0, stream>>>(x, ws, out);
}